// Round 7
// baseline (3424.517 us; speedup 1.0000x reference)
//
#include <hip/hip_runtime.h>

#define NBLK 64
#define NTHR 256
#define SEQ  512
#define BAT  64
#define NINP 256
#define NHID 512
#define LDG  2048   // 4*NHID
#define GOLD 0x9E3779B9u

typedef __attribute__((ext_vector_type(8))) short short8;
typedef __attribute__((ext_vector_type(4))) float f32x4;
typedef __attribute__((ext_vector_type(4))) unsigned int uint4v;

static __device__ __forceinline__ unsigned short f2bf(float x) {
    return __builtin_bit_cast(unsigned short, (__bf16)x);
}
static __device__ __forceinline__ float sigm(float x)  { return 1.0f / (1.0f + __expf(-x)); }
static __device__ __forceinline__ float tanh_(float x) { return 2.0f / (1.0f + __expf(-2.0f * x)) - 1.0f; }

// L3-coherent 16B ops (bypass L1/L2), no implicit wait.
static __device__ __forceinline__ void cload(uint4v& d, const uint4v* p) {
    asm volatile("global_load_dwordx4 %0, %1, off sc0 sc1" : "=v"(d) : "v"(p) : "memory");
}
static __device__ __forceinline__ void cstore(uint4v v, uint4v* p) {
    asm volatile("global_store_dwordx4 %0, %1, off sc0 sc1" :: "v"(p), "v"(v) : "memory");
}

// d_ws: [0, 256KB) h chunk buffer.
// Chunk (16B) = {d0,d1: 4 bf16 h values, tag = t+1, ck = d0+d1+(t+1)*GOLD}.
// Index: ((slot*NBLK + prodBlk)*BAT + row)*2 + half   (slot = t&1 of producing step).
// Self-validating chunks: ONE L3 round trip replaces flag-ack + flag-poll + h-load.
__global__ __launch_bounds__(NTHR, 1)
void lstm_persistent(const float* __restrict__ x, const float* __restrict__ W,
                     const float* __restrict__ U, const float* __restrict__ bias,
                     float* __restrict__ out, uint4v* __restrict__ hbuf)
{
    __shared__ short8 lds_s[4 * 16];   // per-wave 256B transpose staging (wave-private)

    const int bk   = blockIdx.x;
    const int tid  = threadIdx.x;
    const int w    = tid >> 6;
    const int lane = tid & 63;
    const int c16  = lane & 15;
    const int rq   = lane >> 4;

    const int col0 = (c16 >> 3) * NHID + (c16 & 7) + bk * 8;   // i (c16<8) or f
    const int col1 = col0 + 2 * NHID;                           // g or o

    // ---- one-time: U,W slices into register B-fragments ----
    short8 ut[2][16];
#pragma unroll
    for (int kb = 0; kb < 16; ++kb) {
        const int k0 = kb * 32 + rq * 8;
        short8 v0, v1;
#pragma unroll
        for (int j = 0; j < 8; ++j) {
            v0[j] = (short)f2bf(U[(size_t)(k0 + j) * LDG + col0]);
            v1[j] = (short)f2bf(U[(size_t)(k0 + j) * LDG + col1]);
        }
        ut[0][kb] = v0; ut[1][kb] = v1;
    }
    short8 wt[2][8];
#pragma unroll
    for (int kb = 0; kb < 8; ++kb) {
        const int k0 = kb * 32 + rq * 8;
        short8 v0, v1;
#pragma unroll
        for (int j = 0; j < 8; ++j) {
            v0[j] = (short)f2bf(W[(size_t)(k0 + j) * LDG + col0]);
            v1[j] = (short)f2bf(W[(size_t)(k0 + j) * LDG + col1]);
        }
        wt[0][kb] = v0; wt[1][kb] = v1;
    }
    const float bias0 = bias[col0];
    const float bias1 = bias[col1];

    const int  arow  = w * 16 + c16;
    const bool lower = (c16 < 8);
    const bool up    = (c16 & 8);
    const int  hcol  = bk * 8 + (c16 & 7);
    float cst[4] = {0.f, 0.f, 0.f, 0.f};

    float* hout  = out + (size_t)SEQ * BAT * NHID;
    float* cout_ = hout + BAT * NHID;

    unsigned short* lds_w = (unsigned short*)&lds_s[w * 16];

    for (int t = 0; t < SEQ; ++t) {
        const int pR = (t + 1) & 1;   // slot holding h(t-1)
        const int pW = t & 1;         // slot receiving h(t)

        // ---------- x @ W (plain loads; overlaps other blocks' chunk flight) ----------
        f32x4 acc[2][4];
#pragma unroll
        for (int nt = 0; nt < 2; ++nt)
#pragma unroll
            for (int ch = 0; ch < 4; ++ch) acc[nt][ch] = (f32x4){0.f, 0.f, 0.f, 0.f};

        {
            const float* xr = x + ((size_t)t * BAT + arow) * NINP + rq * 8;
#pragma unroll
            for (int kb = 0; kb < 8; ++kb) {
                f32x4 a0 = *(const f32x4*)(xr + kb * 32);
                f32x4 a1 = *(const f32x4*)(xr + kb * 32 + 4);
                short8 xa;
#pragma unroll
                for (int j = 0; j < 4; ++j) {
                    xa[j]     = (short)f2bf(a0[j]);
                    xa[j + 4] = (short)f2bf(a1[j]);
                }
                const int ch = kb & 3;
                acc[0][ch] = __builtin_amdgcn_mfma_f32_16x16x32_bf16(xa, wt[0][kb], acc[0][ch], 0, 0, 0);
                acc[1][ch] = __builtin_amdgcn_mfma_f32_16x16x32_bf16(xa, wt[1][kb], acc[1][ch], 0, 0, 0);
            }
        }

        if (t > 0) {
            // ---------- poll the self-validating h chunks (single round trip) ----------
            const uint4v* base = hbuf + ((size_t)pR * NBLK * BAT + arow) * 2;
            const unsigned tagv = (unsigned)t;
            const unsigned ckt  = tagv * GOLD;
            uint4v chnk[32];
            for (;;) {
#pragma unroll
                for (int kb = 0; kb < 16; ++kb) {
                    const uint4v* cp = base + (size_t)(kb * 4 + rq) * (BAT * 2);
                    cload(chnk[2 * kb],     cp);
                    cload(chnk[2 * kb + 1], cp + 1);
                }
                asm volatile("s_waitcnt vmcnt(0)" ::: "memory");
                bool ok = true;
#pragma unroll
                for (int i = 0; i < 32; ++i)
                    ok = ok && (chnk[i].z == tagv) &&
                         (chnk[i].w == chnk[i].x + chnk[i].y + ckt);
                if (__all(ok)) break;
            }
            __builtin_amdgcn_sched_barrier(0);

            // ---------- h @ U ----------
#pragma unroll
            for (int kb = 0; kb < 16; ++kb) {
                union { uint4v u; short8 s; } a;
                a.u = (uint4v){chnk[2 * kb].x,     chnk[2 * kb].y,
                               chnk[2 * kb + 1].x, chnk[2 * kb + 1].y};
                const int ch = kb & 3;
                acc[0][ch] = __builtin_amdgcn_mfma_f32_16x16x32_bf16(a.s, ut[0][kb], acc[0][ch], 0, 0, 0);
                acc[1][ch] = __builtin_amdgcn_mfma_f32_16x16x32_bf16(a.s, ut[1][kb], acc[1][ch], 0, 0, 0);
            }
        }
        // t == 0: h(-1) = 0, h@U contributes nothing -> skipped entirely.

        f32x4 gif = acc[0][0] + acc[0][1] + acc[0][2] + acc[0][3];
        f32x4 ggo = acc[1][0] + acc[1][1] + acc[1][2] + acc[1][3];
#pragma unroll
        for (int j = 0; j < 4; ++j) { gif[j] += bias0; ggo[j] += bias1; }

        // ---- gate exchange + nonlinearity ----
        f32x4 oif, ogo;
#pragma unroll
        for (int j = 0; j < 4; ++j) {
            oif[j] = __shfl_xor(gif[j], 8, 64);
            ogo[j] = __shfl_xor(ggo[j], 8, 64);
        }
        float hv[4];
#pragma unroll
        for (int j = 0; j < 4; ++j) {
            const float gi = up ? oif[j] : gif[j];
            const float gf = up ? gif[j] : oif[j];
            const float gg = up ? ogo[j] : ggo[j];
            const float go = up ? ggo[j] : ogo[j];
            const float iv = sigm(gi);
            const float fv = sigm(gf);
            const float gv = tanh_(gg);
            const float ov = sigm(go);
            const float cn = fv * cst[j] + iv * gv;
            cst[j] = cn;
            hv[j] = ov * tanh_(cn);
        }

        // ---------- publish h(t): transpose -> self-validating chunks, fire & forget ----------
        if (t < SEQ - 1) {
            if (lower) {
#pragma unroll
                for (int j = 0; j < 4; ++j)
                    lds_w[(rq * 4 + j) * 8 + c16] = f2bf(hv[j]);
            }
            __builtin_amdgcn_sched_barrier(0);
            if (lane < 32) {
                const int row  = lane >> 1;      // 0..15 within wave
                const int half = lane & 1;       // which 4 cols
                const unsigned int* lp = (const unsigned int*)(lds_w + row * 8 + half * 4);
                const unsigned d0 = lp[0], d1 = lp[1];   // compiler inserts lgkmcnt
                const unsigned tg = (unsigned)(t + 1);
                uint4v c;
                c.x = d0; c.y = d1; c.z = tg; c.w = d0 + d1 + tg * GOLD;
                cstore(c, hbuf + ((size_t)(pW * NBLK + bk) * BAT + (w * 16 + row)) * 2 + half);
            }
            // NO ack wait, NO flag: consumers validate the chunks themselves.
        }

        // ---------- output stores (off the critical path) ----------
        if (lower) {
#pragma unroll
            for (int j = 0; j < 4; ++j) {
                const int batch = w * 16 + rq * 4 + j;
                out[((size_t)t * BAT + batch) * NHID + hcol] = hv[j];
                if (t == SEQ - 1) {
                    hout[batch * NHID + hcol]  = hv[j];
                    cout_[batch * NHID + hcol] = cst[j];
                }
            }
        }
    }
}

extern "C" void kernel_launch(void* const* d_in, const int* in_sizes, int n_in,
                              void* d_out, int out_size, void* d_ws, size_t ws_size,
                              hipStream_t stream) {
    (void)in_sizes; (void)n_in; (void)out_size; (void)ws_size;
    const float* x  = (const float*)d_in[0];
    const float* W  = (const float*)d_in[1];
    const float* U  = (const float*)d_in[2];
    const float* b  = (const float*)d_in[3];
    float* out = (float*)d_out;

    uint4v* hbuf = (uint4v*)d_ws;

    // Zero all tags every launch: stale/poisoned chunks can never false-match.
    hipMemsetAsync(d_ws, 0, 2 * NBLK * BAT * 2 * 16, stream);
    hipLaunchKernelGGL(lstm_persistent, dim3(NBLK), dim3(NTHR), 0, stream,
                       x, W, U, b, out, hbuf);
}